// Round 2
// baseline (255.229 us; speedup 1.0000x reference)
//
#include <hip/hip_runtime.h>

#define N_DIM 16384
#define C_DIM 10000
#define D_DIM 128
#define CT 79            // c-tiles of 128 (ceil(10000/128))
#define C_PAD 10240      // mu rows padded/zeroed by prep
#define BM 64            // z rows per block tile
#define BN 128           // mu rows per block tile (32 per wave)
#define MT 256           // 16384/64 m-tiles
#define ZPB 2048         // z prep blocks  (8 rows each)
#define MPB 1280         // mu prep blocks (8 rows each)

typedef __attribute__((ext_vector_type(8))) short bf16x8;
typedef __attribute__((ext_vector_type(4))) float f32x4;
typedef __attribute__((ext_vector_type(2))) unsigned int uint2v;

static __device__ __forceinline__ unsigned short f2bf(float x) {
  unsigned int u = __float_as_uint(x);
  u += 0x7fffu + ((u >> 16) & 1u);   // round-to-nearest-even
  return (unsigned short)(u >> 16);
}

// --- fused prep, one dispatch.
// z  -> bf16 LINEAR, pre-scaled by iv=exp(-lc); atbl[n] = -0.5*||z||^2*iv
// mu -> bf16 LINEAR (main reads fragments straight from global now — the
//       swizzle existed only for global_load_lds, which is gone);
//       btbl[c] (lse added in main). last block: lse = logsumexp(prior)
__global__ __launch_bounds__(256) void prep_kernel(
    const float* __restrict__ z, const float* __restrict__ mu,
    const float* __restrict__ log_cov, const float* __restrict__ prior,
    unsigned short* __restrict__ zb, unsigned short* __restrict__ mub,
    float* __restrict__ atbl, float* __restrict__ btbl, float* __restrict__ lse_out) {
  const int bid = blockIdx.x;
  const int tid = threadIdx.x;
  if (bid < ZPB + MPB) {
    const bool isz = bid < ZPB;
    const int lane = tid & 63;
    const int row = (isz ? bid : bid - ZPB) * 8 + ((tid >> 6) << 1) + (lane >> 5);
    const int col = (lane & 31) * 4;      // float index within row
    const int nrows = isz ? N_DIM : C_DIM;
    f32x4 v = {0.f, 0.f, 0.f, 0.f};
    if (row < nrows)
      v = *(const f32x4*)((isz ? z : mu) + (size_t)row * D_DIM + col);
    float ss = v[0]*v[0] + v[1]*v[1] + v[2]*v[2] + v[3]*v[3];
    #pragma unroll
    for (int off = 16; off; off >>= 1) ss += __shfl_down(ss, off, 32);
    float lc = log_cov[0];
    float iv = expf(-lc);
    if (isz) { v[0]*=iv; v[1]*=iv; v[2]*=iv; v[3]*=iv; }   // fold iv into z
    uint2v packed;
    packed[0] = (unsigned int)f2bf(v[0]) | ((unsigned int)f2bf(v[1]) << 16);
    packed[1] = (unsigned int)f2bf(v[2]) | ((unsigned int)f2bf(v[3]) << 16);
    int cb = (lane & 31) * 8;             // byte col of this 8B chunk
    *(uint2v*)((char*)(isz ? zb : mub) + (size_t)row * 256 + cb) = packed;  // linear
    if ((lane & 31) == 0) {
      if (isz) {
        atbl[row] = -0.5f * ss * iv;
      } else {
        btbl[row] = (row < C_DIM)
            ? (prior[row] - 0.5f * ss * iv - 0.5f * (float)D_DIM * lc) : 0.f;
      }
    }
  } else {
    __shared__ float red[256];
    const f32x4* p4 = (const f32x4*)prior;
    float m = -1e30f;
    for (int i = tid; i < C_DIM / 4; i += 256) {
      f32x4 v = p4[i];
      m = fmaxf(fmaxf(fmaxf(m, v[0]), fmaxf(v[1], v[2])), v[3]);
    }
    red[tid] = m; __syncthreads();
    for (int s = 128; s; s >>= 1) {
      if (tid < s) red[tid] = fmaxf(red[tid], red[tid + s]);
      __syncthreads();
    }
    float mx = red[0]; __syncthreads();
    float sum = 0.f;
    for (int i = tid; i < C_DIM / 4; i += 256) {
      f32x4 v = p4[i];
      sum += expf(v[0] - mx) + expf(v[1] - mx) + expf(v[2] - mx) + expf(v[3] - mx);
    }
    red[tid] = sum; __syncthreads();
    for (int s = 128; s; s >>= 1) {
      if (tid < s) red[tid] += red[tid + s];
      __syncthreads();
    }
    if (tid == 0) *lse_out = mx + logf(red[0]);
  }
}

// --- main: 64m x 128c block tile, BARRIER-FREE. Each wave owns a 32c x 64m
// sub-tile (c-split): mu fragment reads are wave-private straight from
// L2-resident mub (8 KB/wave — same total as LDS staging, minus the barrier
// and its vmcnt(0) drain); the z slab (16 KB) is shared by all 4 waves via L1.
// LDS is used only for each wave's PRIVATE output transpose (8 KB/wave), so
// there is no __syncthreads() anywhere: all 16 resident waves/CU run
// independent load->MFMA->transpose->store streams, decorrelating the HBM
// store queue (the fill-kernel regime).
// Epilogue stores 128 B per row = exactly one cache line, 1 KB/instruction.
__global__ __launch_bounds__(256, 4) void lda_main_kernel(
    const unsigned short* __restrict__ zb, const unsigned short* __restrict__ mub,
    const float* __restrict__ atbl, const float* __restrict__ btbl,
    const float* __restrict__ lse_p, const float* __restrict__ log_cov,
    float* __restrict__ out) {
  __shared__ char lds[4 * 8192];      // 32 KB total; 8 KB wave-private regions

  const int ct = blockIdx.x;          // 0..78
  const int mt = blockIdx.y;          // 0..255
  const int tid = threadIdx.x;
  const int wid = tid >> 6;
  const int lane = tid & 63;
  const int l15 = lane & 15;
  const int lq = lane >> 4;
  const int l7 = lane & 7;
  const int rbase = mt * BM;
  const int cwave = ct * BN + wid * 32;   // this wave's c-window (32 wide)

  // per-lane c-terms for the store phase: c = cwave + l7*4 .. +3
  const float lse = lse_p[0];
  f32x4 btv = *(const f32x4*)&btbl[cwave + l7 * 4];
  btv[0] -= lse; btv[1] -= lse; btv[2] -= lse; btv[3] -= lse;

  // MFMA: acc[cf][nf]; A=mu (M=c, 2 frags), B=z (N=m, 4 frags), K chunks kk
  f32x4 acc[2][4] = {};
  #pragma unroll
  for (int kk = 0; kk < 4; ++kk) {
    const int kb = kk * 64 + lq * 16;   // byte offset within 256B row
    bf16x8 mf[2];
    #pragma unroll
    for (int cf = 0; cf < 2; ++cf)
      mf[cf] = *(const bf16x8*)((const char*)mub +
                 (size_t)(cwave + cf * 16 + l15) * 256 + kb);
    bf16x8 zf[4];
    #pragma unroll
    for (int nf = 0; nf < 4; ++nf)
      zf[nf] = *(const bf16x8*)((const char*)zb +
                 (size_t)(rbase + nf * 16 + l15) * 256 + kb);
    #pragma unroll
    for (int cf = 0; cf < 2; ++cf)
      #pragma unroll
      for (int nf = 0; nf < 4; ++nf)
        acc[cf][nf] = __builtin_amdgcn_mfma_f32_16x16x32_bf16(
            mf[cf], zf[nf], acc[cf][nf], 0, 0, 0);
  }

  // wave-private transpose: LDS tile [64 m][32 c] f32, 128B rows,
  // XOR-swizzled (byte ^= (m&7)<<4) to kill the 128B-stride write conflict.
  char* wlds = lds + wid * 8192;
  #pragma unroll
  for (int cf = 0; cf < 2; ++cf)
    #pragma unroll
    for (int nf = 0; nf < 4; ++nf) {
      int m = nf * 16 + l15;                  // local m row (C/D col = l15)
      int cb4 = (cf * 16 + lq * 4) * 4;       // byte col in 128B row
      *(f32x4*)(wlds + m * 128 + (cb4 ^ ((m & 7) << 4))) = acc[cf][nf];
    }

  // read back row-major (own region, no barrier): 8 rows x 128B per instr,
  // store 128B contiguous per row (one full cache line)
  const int cg = cwave + l7 * 4;
  #pragma unroll
  for (int i = 0; i < 8; ++i) {
    int m = i * 8 + (lane >> 3);
    int rowg = rbase + m;
    f32x4 t = *(const f32x4*)(wlds + m * 128 + ((l7 * 16) ^ ((m & 7) << 4)));
    float av = atbl[rowg];
    if (cg < C_DIM) {                 // divergent only in the last c-tile
      f32x4 v;
      #pragma unroll
      for (int r = 0; r < 4; ++r) v[r] = av + btv[r] + t[r];
      __builtin_nontemporal_store(v, (f32x4*)(out + (size_t)rowg * C_DIM + cg));
    }
  }
}

extern "C" void kernel_launch(void* const* d_in, const int* in_sizes, int n_in,
                              void* d_out, int out_size, void* d_ws, size_t ws_size,
                              hipStream_t stream) {
  const float* z     = (const float*)d_in[0];
  const float* mu    = (const float*)d_in[1];
  const float* lcov  = (const float*)d_in[2];
  const float* prior = (const float*)d_in[3];
  float* out = (float*)d_out;

  char* w = (char*)d_ws;
  unsigned short* zb  = (unsigned short*)w;                       // 4,194,304 B
  unsigned short* mub = (unsigned short*)(w + 4194304);           // 2,621,440 B
  float* atbl = (float*)(w + 4194304 + 2621440);                  // 65,536 B
  float* btbl = atbl + N_DIM;                                     // 40,960 B
  float* lse  = btbl + C_PAD;                                     // 4 B

  prep_kernel<<<ZPB + MPB + 1, 256, 0, stream>>>(z, mu, lcov, prior,
                                                 zb, mub, atbl, btbl, lse);
  dim3 grid(CT, MT);   // 79 x 256 = 20224 tiles
  lda_main_kernel<<<grid, 256, 0, stream>>>(zb, mub, atbl, btbl, lse, lcov, out);
}

// Round 4
// 174.874 us; speedup vs baseline: 1.4595x; 1.4595x over previous
//
#include <hip/hip_runtime.h>

#define N_DIM 16384
#define C_DIM 10000
#define D_DIM 128
#define CT 79            // c-tiles of 128 (ceil(10000/128))
#define C_PAD 10240      // mu rows padded/zeroed by prep
#define BM 64            // z rows per block tile
#define BN 128           // mu rows per block tile
#define MT 256           // 16384/64 m-tiles
#define ZPB 2048         // z prep blocks  (8 rows each)
#define MPB 1280         // mu prep blocks (8 rows each)

typedef __attribute__((ext_vector_type(8))) short bf16x8;
typedef __attribute__((ext_vector_type(4))) float f32x4;
typedef __attribute__((ext_vector_type(2))) unsigned int uint2v;

static __device__ __forceinline__ unsigned short f2bf(float x) {
  unsigned int u = __float_as_uint(x);
  u += 0x7fffu + ((u >> 16) & 1u);   // round-to-nearest-even
  return (unsigned short)(u >> 16);
}

// --- fused prep, one dispatch (identical to the verified R1 version).
// z  -> bf16 LINEAR, pre-scaled by iv=exp(-lc); atbl[n] = -0.5*||z||^2*iv
// mu -> bf16 PRE-SWIZZLED (byte col ^= (row&7)<<4) for main's linear
//       global_load_lds staging (both-sides-or-neither, G21);
//       btbl[c] (lse added in main). last block: lse = logsumexp(prior)
__global__ __launch_bounds__(256) void prep_kernel(
    const float* __restrict__ z, const float* __restrict__ mu,
    const float* __restrict__ log_cov, const float* __restrict__ prior,
    unsigned short* __restrict__ zb, unsigned short* __restrict__ mub,
    float* __restrict__ atbl, float* __restrict__ btbl, float* __restrict__ lse_out) {
  const int bid = blockIdx.x;
  const int tid = threadIdx.x;
  if (bid < ZPB + MPB) {
    const bool isz = bid < ZPB;
    const int lane = tid & 63;
    const int row = (isz ? bid : bid - ZPB) * 8 + ((tid >> 6) << 1) + (lane >> 5);
    const int col = (lane & 31) * 4;      // float index within row
    const int nrows = isz ? N_DIM : C_DIM;
    f32x4 v = {0.f, 0.f, 0.f, 0.f};
    if (row < nrows)
      v = *(const f32x4*)((isz ? z : mu) + (size_t)row * D_DIM + col);
    float ss = v[0]*v[0] + v[1]*v[1] + v[2]*v[2] + v[3]*v[3];
    #pragma unroll
    for (int off = 16; off; off >>= 1) ss += __shfl_down(ss, off, 32);
    float lc = log_cov[0];
    float iv = expf(-lc);
    if (isz) { v[0]*=iv; v[1]*=iv; v[2]*=iv; v[3]*=iv; }   // fold iv into z
    uint2v packed;
    packed[0] = (unsigned int)f2bf(v[0]) | ((unsigned int)f2bf(v[1]) << 16);
    packed[1] = (unsigned int)f2bf(v[2]) | ((unsigned int)f2bf(v[3]) << 16);
    int cb = (lane & 31) * 8;             // byte col of this 8B chunk
    if (isz) {
      *(uint2v*)((char*)zb + (size_t)row * 256 + cb) = packed;               // linear
    } else {
      *(uint2v*)((char*)mub + (size_t)row * 256 + (cb ^ ((row & 7) << 4))) = packed;
    }
    if ((lane & 31) == 0) {
      if (isz) {
        atbl[row] = -0.5f * ss * iv;
      } else {
        btbl[row] = (row < C_DIM)
            ? (prior[row] - 0.5f * ss * iv - 0.5f * (float)D_DIM * lc) : 0.f;
      }
    }
  } else {
    __shared__ float red[256];
    const f32x4* p4 = (const f32x4*)prior;
    float m = -1e30f;
    for (int i = tid; i < C_DIM / 4; i += 256) {
      f32x4 v = p4[i];
      m = fmaxf(fmaxf(fmaxf(m, v[0]), fmaxf(v[1], v[2])), v[3]);
    }
    red[tid] = m; __syncthreads();
    for (int s = 128; s; s >>= 1) {
      if (tid < s) red[tid] = fmaxf(red[tid], red[tid + s]);
      __syncthreads();
    }
    float mx = red[0]; __syncthreads();
    float sum = 0.f;
    for (int i = tid; i < C_DIM / 4; i += 256) {
      f32x4 v = p4[i];
      sum += expf(v[0] - mx) + expf(v[1] - mx) + expf(v[2] - mx) + expf(v[3] - mx);
    }
    red[tid] = sum; __syncthreads();
    for (int s = 128; s; s >>= 1) {
      if (tid < s) red[tid] += red[tid + s];
      __syncthreads();
    }
    if (tid == 0) *lse_out = mx + logf(red[0]);
  }
}

// --- main: 64m x 128c tile (verified R1 structure) with a DIRECT-STORE
// epilogue: no second barrier, no LDS transpose round-trip. Each store
// instruction writes 16 rows x 64B contiguous (1 KB); consecutive a-fragments
// write the adjacent 64B halves of each 128B line back-to-back, so the
// write-back L2 merges them into full lines before HBM eviction. The mu LDS
// region is read-only after the single staging barrier -- zero LDS lifecycle
// hazards. 32 KB LDS, <=128 VGPR -> 4 blocks/CU (16 waves).
__global__ __launch_bounds__(256, 4) void lda_main_kernel(
    const unsigned short* __restrict__ zb, const unsigned short* __restrict__ mub,
    const float* __restrict__ atbl, const float* __restrict__ btbl,
    const float* __restrict__ lse_p, const float* __restrict__ log_cov,
    float* __restrict__ out) {
  __shared__ char lds[BN * 256];      // 32 KB mu tile (read-only after barrier)

  const int ct = blockIdx.x;          // 0..78
  const int mt = blockIdx.y;          // 0..255
  const int tid = threadIdx.x;
  const int rbase = mt * BM;
  const int cbase = ct * BN;
  const int wid = tid >> 6;
  const int lane = tid & 63;
  const int l15 = lane & 15;
  const int lq = lane >> 4;

  // stage mu tile: 8 issues x 1KB per wave, linear dest (global pre-swizzled)
  {
    const char* gm = (const char*)mub + (size_t)cbase * 256 + wid * 8192 + lane * 16;
    char* lm = lds + wid * 8192;
    #pragma unroll
    for (int it = 0; it < 8; ++it)
      __builtin_amdgcn_global_load_lds(
          (const __attribute__((address_space(1))) void*)(gm + it * 1024),
          (__attribute__((address_space(3))) void*)(lm + it * 1024), 16, 0, 0);
  }

  // z fragments from global (16KB slab; L1/L2-resident across the block's waves)
  const int zrow = rbase + wid * 16 + l15;     // this lane's z row (MFMA N=col=l15)
  bf16x8 zf[4];
  #pragma unroll
  for (int kk = 0; kk < 4; ++kk)
    zf[kk] = *(const bf16x8*)((const char*)zb + (size_t)zrow * 256 + kk * 64 + lq * 16);

  // per-row a-term (hoisted; overlaps the staging drain). lse folded in here.
  const float avl = atbl[zrow] - lse_p[0];

  __syncthreads();    // mu staged -- the only barrier

  // MFMA: acc[a] over 8 c-fragments; A=mu (M=c), B=z (N=m)
  f32x4 acc[8] = {};
  #pragma unroll
  for (int kk = 0; kk < 4; ++kk) {
    const int kbyte = kk * 64 + lq * 16;
    bf16x8 mf[8];
    #pragma unroll
    for (int a = 0; a < 8; ++a) {
      int row = a * 16 + l15;
      mf[a] = *(const bf16x8*)(lds + row * 256 + (kbyte ^ ((row & 7) << 4)));
    }
    #pragma unroll
    for (int a = 0; a < 8; ++a)
      acc[a] = __builtin_amdgcn_mfma_f32_16x16x32_bf16(mf[a], zf[kk], acc[a], 0, 0, 0);
  }

  // direct fragment stores: D[row=c=lq*4+r][col=m=l15] -> out[zrow][cg+r].
  // Per instruction: 16 rows x 64B contiguous; a and a+1 fill adjacent 64B
  // halves of the same 128B lines (L2 write-combines).
  const size_t outrow = (size_t)zrow * C_DIM;
  #pragma unroll
  for (int a = 0; a < 8; ++a) {
    const int cg = cbase + a * 16 + lq * 4;
    f32x4 bt = *(const f32x4*)&btbl[cg];    // btbl padded to C_PAD -- safe
    if (cg < C_DIM) {                       // masked only in the last c-tile
      f32x4 v;
      #pragma unroll
      for (int r = 0; r < 4; ++r) v[r] = avl + bt[r] + acc[a][r];
      __builtin_nontemporal_store(v, (f32x4*)(out + outrow + cg));
    }
  }
}

extern "C" void kernel_launch(void* const* d_in, const int* in_sizes, int n_in,
                              void* d_out, int out_size, void* d_ws, size_t ws_size,
                              hipStream_t stream) {
  const float* z     = (const float*)d_in[0];
  const float* mu    = (const float*)d_in[1];
  const float* lcov  = (const float*)d_in[2];
  const float* prior = (const float*)d_in[3];
  float* out = (float*)d_out;

  char* w = (char*)d_ws;
  unsigned short* zb  = (unsigned short*)w;                       // 4,194,304 B
  unsigned short* mub = (unsigned short*)(w + 4194304);           // 2,621,440 B
  float* atbl = (float*)(w + 4194304 + 2621440);                  // 65,536 B
  float* btbl = atbl + N_DIM;                                     // 40,960 B
  float* lse  = btbl + C_PAD;                                     // 4 B

  prep_kernel<<<ZPB + MPB + 1, 256, 0, stream>>>(z, mu, lcov, prior,
                                                 zb, mub, atbl, btbl, lse);
  dim3 grid(CT, MT);   // 79 x 256 = 20224 tiles
  lda_main_kernel<<<grid, 256, 0, stream>>>(zb, mub, atbl, btbl, lse, lcov, out);
}

// Round 5
// 127.339 us; speedup vs baseline: 2.0043x; 1.3733x over previous
//
#include <hip/hip_runtime.h>

#define N_DIM 16384
#define C_DIM 10000
#define D_DIM 128
#define CT 79            // c-tiles of 128 (ceil(10000/128))
#define C_PAD 10240      // mu rows padded/zeroed by prep
#define BM 64            // z rows per block tile
#define BN 128           // mu rows per block tile
#define MT 256           // 16384/64 m-tiles
#define ZPB 2048         // z prep blocks  (8 rows each)
#define MPB 1280         // mu prep blocks (8 rows each)

typedef __attribute__((ext_vector_type(8))) short bf16x8;
typedef __attribute__((ext_vector_type(4))) float f32x4;
typedef __attribute__((ext_vector_type(2))) unsigned int uint2v;

static __device__ __forceinline__ unsigned short f2bf(float x) {
  unsigned int u = __float_as_uint(x);
  u += 0x7fffu + ((u >> 16) & 1u);   // round-to-nearest-even
  return (unsigned short)(u >> 16);
}

// --- fused prep, one dispatch (identical to the verified R1 version).
// z  -> bf16 LINEAR, pre-scaled by iv=exp(-lc); atbl[n] = -0.5*||z||^2*iv
// mu -> bf16 PRE-SWIZZLED (byte col ^= (row&7)<<4) for main's linear
//       global_load_lds staging (both-sides-or-neither, G21);
//       btbl[c] (lse added in main). last block: lse = logsumexp(prior)
__global__ __launch_bounds__(256) void prep_kernel(
    const float* __restrict__ z, const float* __restrict__ mu,
    const float* __restrict__ log_cov, const float* __restrict__ prior,
    unsigned short* __restrict__ zb, unsigned short* __restrict__ mub,
    float* __restrict__ atbl, float* __restrict__ btbl, float* __restrict__ lse_out) {
  const int bid = blockIdx.x;
  const int tid = threadIdx.x;
  if (bid < ZPB + MPB) {
    const bool isz = bid < ZPB;
    const int lane = tid & 63;
    const int row = (isz ? bid : bid - ZPB) * 8 + ((tid >> 6) << 1) + (lane >> 5);
    const int col = (lane & 31) * 4;      // float index within row
    const int nrows = isz ? N_DIM : C_DIM;
    f32x4 v = {0.f, 0.f, 0.f, 0.f};
    if (row < nrows)
      v = *(const f32x4*)((isz ? z : mu) + (size_t)row * D_DIM + col);
    float ss = v[0]*v[0] + v[1]*v[1] + v[2]*v[2] + v[3]*v[3];
    #pragma unroll
    for (int off = 16; off; off >>= 1) ss += __shfl_down(ss, off, 32);
    float lc = log_cov[0];
    float iv = expf(-lc);
    if (isz) { v[0]*=iv; v[1]*=iv; v[2]*=iv; v[3]*=iv; }   // fold iv into z
    uint2v packed;
    packed[0] = (unsigned int)f2bf(v[0]) | ((unsigned int)f2bf(v[1]) << 16);
    packed[1] = (unsigned int)f2bf(v[2]) | ((unsigned int)f2bf(v[3]) << 16);
    int cb = (lane & 31) * 8;             // byte col of this 8B chunk
    if (isz) {
      *(uint2v*)((char*)zb + (size_t)row * 256 + cb) = packed;               // linear
    } else {
      *(uint2v*)((char*)mub + (size_t)row * 256 + (cb ^ ((row & 7) << 4))) = packed;
    }
    if ((lane & 31) == 0) {
      if (isz) {
        atbl[row] = -0.5f * ss * iv;
      } else {
        btbl[row] = (row < C_DIM)
            ? (prior[row] - 0.5f * ss * iv - 0.5f * (float)D_DIM * lc) : 0.f;
      }
    }
  } else {
    __shared__ float red[256];
    const f32x4* p4 = (const f32x4*)prior;
    float m = -1e30f;
    for (int i = tid; i < C_DIM / 4; i += 256) {
      f32x4 v = p4[i];
      m = fmaxf(fmaxf(fmaxf(m, v[0]), fmaxf(v[1], v[2])), v[3]);
    }
    red[tid] = m; __syncthreads();
    for (int s = 128; s; s >>= 1) {
      if (tid < s) red[tid] = fmaxf(red[tid], red[tid + s]);
      __syncthreads();
    }
    float mx = red[0]; __syncthreads();
    float sum = 0.f;
    for (int i = tid; i < C_DIM / 4; i += 256) {
      f32x4 v = p4[i];
      sum += expf(v[0] - mx) + expf(v[1] - mx) + expf(v[2] - mx) + expf(v[3] - mx);
    }
    red[tid] = sum; __syncthreads();
    for (int s = 128; s; s >>= 1) {
      if (tid < s) red[tid] += red[tid + s];
      __syncthreads();
    }
    if (tid == 0) *lse_out = mx + logf(red[0]);
  }
}

// --- main: verified R1 structure (64m x 128c tile, LDS mu staging, LDS
// transpose epilogue with 512B store runs), now at 5 blocks/CU:
// 5 x 32 KB = exactly 160 KB LDS, and __launch_bounds__(256,5) caps VGPR at
// 102. To fit, the k-loop pairs mu-fragment loads with their MFMAs (live mf
// = 8 VGPR instead of 32). Deeper block overlap keeps the HBM store queue
// fed across block-start stage/vmcnt/barrier phases.
__global__ __launch_bounds__(256, 5) void lda_main_kernel(
    const unsigned short* __restrict__ zb, const unsigned short* __restrict__ mub,
    const float* __restrict__ atbl, const float* __restrict__ btbl,
    const float* __restrict__ lse_p, const float* __restrict__ log_cov,
    float* __restrict__ out) {
  __shared__ char lds[BN * 256];      // 32 KB (mu tile; later 64x128 f32 out tile)

  const int ct = blockIdx.x;          // 0..78
  const int mt = blockIdx.y;          // 0..255
  const int tid = threadIdx.x;
  const int rbase = mt * BM;
  const int cbase = ct * BN;
  const int wid = tid >> 6;
  const int lane = tid & 63;
  const int l15 = lane & 15;
  const int lq = lane >> 4;

  // stage mu tile: 8 issues x 1KB per wave, linear dest (global pre-swizzled)
  {
    const char* gm = (const char*)mub + (size_t)cbase * 256 + wid * 8192 + lane * 16;
    char* lm = lds + wid * 8192;
    #pragma unroll
    for (int it = 0; it < 8; ++it)
      __builtin_amdgcn_global_load_lds(
          (const __attribute__((address_space(1))) void*)(gm + it * 1024),
          (__attribute__((address_space(3))) void*)(lm + it * 1024), 16, 0, 0);
  }

  // z fragments from global (16KB slab; L1/L2-resident across the block's waves)
  const int zrow = rbase + wid * 16 + l15;     // this lane's z row (MFMA N=col=l15)
  bf16x8 zf[4];
  #pragma unroll
  for (int kk = 0; kk < 4; ++kk)
    zf[kk] = *(const bf16x8*)((const char*)zb + (size_t)zrow * 256 + kk * 64 + lq * 16);

  // per-lane c-terms for the store phase: c = cbase + (lane&31)*4 .. +3
  const int l31 = lane & 31;
  const float lse = lse_p[0];
  f32x4 btv = *(const f32x4*)&btbl[cbase + l31 * 4];
  btv[0] -= lse; btv[1] -= lse; btv[2] -= lse; btv[3] -= lse;

  __syncthreads();    // mu staged

  // MFMA: acc[a] over 8 c-fragments; A=mu (M=c), B=z (N=m).
  // mf loads paired with their MFMAs to cap live mu fragments at 2 (8 VGPR),
  // keeping total allocation under the 102-VGPR / 5-blocks-per-CU budget.
  f32x4 acc[8] = {};
  #pragma unroll
  for (int kk = 0; kk < 4; ++kk) {
    const int kbyte = kk * 64 + lq * 16;
    #pragma unroll
    for (int a = 0; a < 8; a += 2) {
      int r0 = a * 16 + l15;
      int r1 = (a + 1) * 16 + l15;
      bf16x8 m0 = *(const bf16x8*)(lds + r0 * 256 + (kbyte ^ ((r0 & 7) << 4)));
      bf16x8 m1 = *(const bf16x8*)(lds + r1 * 256 + (kbyte ^ ((r1 & 7) << 4)));
      acc[a]     = __builtin_amdgcn_mfma_f32_16x16x32_bf16(m0, zf[kk], acc[a],     0, 0, 0);
      acc[a + 1] = __builtin_amdgcn_mfma_f32_16x16x32_bf16(m1, zf[kk], acc[a + 1], 0, 0, 0);
    }
  }

  __syncthreads();    // all waves done reading mu; LDS becomes the output tile

  // write fragments -> LDS [m][c] (fp32, 512B rows, XOR-swizzled to kill the
  // 512B-stride write conflict)
  const int mloc = wid * 16 + l15;    // this lane's m row (D col = l15)
  #pragma unroll
  for (int a = 0; a < 8; ++a) {
    int cb4 = (a * 16 + lq * 4) * 4;  // byte col in the 512B row
    *(f32x4*)(lds + mloc * 512 + (cb4 ^ ((mloc & 7) << 4))) = acc[a];
  }

  // read back row-major (own rows only -- no barrier), 2 rows per instruction,
  // and store 512B contiguous per half-wave
  const int hl = lane >> 5;
  #pragma unroll
  for (int i = 0; i < 16; i += 2) {
    int m = wid * 16 + i + hl;
    int rowg = rbase + m;
    f32x4 t = *(const f32x4*)(lds + m * 512 + ((l31 * 16) ^ ((m & 7) << 4)));
    float av = atbl[rowg];
    int cg = cbase + l31 * 4;
    if (cg < C_DIM) {                 // divergent only in the last c-tile
      f32x4 v;
      #pragma unroll
      for (int r = 0; r < 4; ++r) v[r] = av + btv[r] + t[r];
      __builtin_nontemporal_store(v, (f32x4*)(out + (size_t)rowg * C_DIM + cg));
    }
  }
}

extern "C" void kernel_launch(void* const* d_in, const int* in_sizes, int n_in,
                              void* d_out, int out_size, void* d_ws, size_t ws_size,
                              hipStream_t stream) {
  const float* z     = (const float*)d_in[0];
  const float* mu    = (const float*)d_in[1];
  const float* lcov  = (const float*)d_in[2];
  const float* prior = (const float*)d_in[3];
  float* out = (float*)d_out;

  char* w = (char*)d_ws;
  unsigned short* zb  = (unsigned short*)w;                       // 4,194,304 B
  unsigned short* mub = (unsigned short*)(w + 4194304);           // 2,621,440 B
  float* atbl = (float*)(w + 4194304 + 2621440);                  // 65,536 B
  float* btbl = atbl + N_DIM;                                     // 40,960 B
  float* lse  = btbl + C_PAD;                                     // 4 B

  prep_kernel<<<ZPB + MPB + 1, 256, 0, stream>>>(z, mu, lcov, prior,
                                                 zb, mub, atbl, btbl, lse);
  dim3 grid(CT, MT);   // 79 x 256 = 20224 tiles
  lda_main_kernel<<<grid, 256, 0, stream>>>(zb, mub, atbl, btbl, lse, lcov, out);
}